// Round 12
// baseline (192.806 us; speedup 1.0000x reference)
//
#include <hip/hip_runtime.h>

#define B_ROWS 14336
#define D_DIM  512
#define C_CLS  7
#define M_CLS  2048

typedef __attribute__((ext_vector_type(4))) float f32x4;

// fp8 scale: fea*64 -> sigma~3.2 in e4m3 range; Gram scaled by 4096
#define FP8_SCALE 64.0f
#define INV_2S2   (2.0f / 4096.0f)

typedef const __attribute__((address_space(1))) char gchar_t;
typedef __attribute__((address_space(3))) char lchar_t;

__device__ __forceinline__ void gload16(const char* g, char* l) {
  // async global->LDS DMA, 16B/lane, dest = wave-uniform base + lane*16
  __builtin_amdgcn_global_load_lds((gchar_t*)g, (lchar_t*)l, 16, 0, 0);
}

// K0: fea->fp8 packed in fragment-order image + row norms + logits + zero zb.
// Image layout: 16B at (r16, kp, l) = byte ((r16*8 + kp)*64 + l)*16, holding
// row r16*16 + (l&15), k-bytes {kp*64 + (l>>4)*8 ..+7} (.x) and {+32..} (.y).
__global__ __launch_bounds__(256) void k_prep(const float* __restrict__ fea,
                                              const float* __restrict__ W,
                                              char* __restrict__ f8p,
                                              float* __restrict__ an,
                                              float* __restrict__ logits,
                                              float* __restrict__ zb) {  // 64 floats
  int t = threadIdx.x, wave = t >> 6, lane = t & 63;
  if (blockIdx.x == 0 && t < 64) zb[t] = 0.f;
  __shared__ char lrow[16 * 528];  // 16 rows x 512B fp8 (+16 pad)

  int r0 = blockIdx.x * 16;
#pragma unroll
  for (int k = 0; k < 4; ++k) {
    int rl = wave * 4 + k;
    int row = r0 + rl;
    const float4* fr4 = (const float4*)(fea + (size_t)row * D_DIM);
    float4 v0 = fr4[lane * 2], v1 = fr4[lane * 2 + 1];

    float p[8];
#pragma unroll
    for (int c = 0; c < 7; ++c) {
      const float4* w4 = (const float4*)(W + c * D_DIM);
      float4 q0 = w4[lane * 2], q1 = w4[lane * 2 + 1];
      p[c] = v0.x * q0.x + v0.y * q0.y + v0.z * q0.z + v0.w * q0.w +
             v1.x * q1.x + v1.y * q1.y + v1.z * q1.z + v1.w * q1.w;
    }
    p[7] = v0.x * v0.x + v0.y * v0.y + v0.z * v0.z + v0.w * v0.w +
           v1.x * v1.x + v1.y * v1.y + v1.z * v1.z + v1.w * v1.w;

#pragma unroll
    for (int c = 0; c < 8; ++c) {
      p[c] += __shfl_xor(p[c], 1);
      p[c] += __shfl_xor(p[c], 2);
      p[c] += __shfl_xor(p[c], 4);
    }
    int v = lane & 7;
    float y = p[0];
    y = (v == 1) ? p[1] : y;
    y = (v == 2) ? p[2] : y;
    y = (v == 3) ? p[3] : y;
    y = (v == 4) ? p[4] : y;
    y = (v == 5) ? p[5] : y;
    y = (v == 6) ? p[6] : y;
    y = (v == 7) ? p[7] : y;
    y += __shfl_xor(y, 8);
    y += __shfl_xor(y, 16);
    y += __shfl_xor(y, 32);
    if (lane < 7) logits[row * 7 + lane] = y;
    else if (lane == 7) an[row] = y;

    int w0 = __builtin_amdgcn_cvt_pk_fp8_f32(v0.x * FP8_SCALE, v0.y * FP8_SCALE, 0, 0);
    w0     = __builtin_amdgcn_cvt_pk_fp8_f32(v0.z * FP8_SCALE, v0.w * FP8_SCALE, w0, 1);
    int w1 = __builtin_amdgcn_cvt_pk_fp8_f32(v1.x * FP8_SCALE, v1.y * FP8_SCALE, 0, 0);
    w1     = __builtin_amdgcn_cvt_pk_fp8_f32(v1.z * FP8_SCALE, v1.w * FP8_SCALE, w1, 1);
    *(int2*)&lrow[rl * 528 + lane * 8] = make_int2(w0, w1);
  }
  __syncthreads();
  int4* outp = (int4*)f8p + (size_t)blockIdx.x * 512;
#pragma unroll
  for (int pi = 0; pi < 2; ++pi) {
    int idx = pi * 256 + t;          // [0,512) = (kp, l)
    int kp = idx >> 6, l = idx & 63;
    int sr = l & 15, qk = l >> 4;
    int2 lo = *(const int2*)&lrow[sr * 528 + kp * 64 + qk * 8];
    int2 hi = *(const int2*)&lrow[sr * 528 + kp * 64 + 32 + qk * 8];
    outp[idx] = make_int4(lo.x, lo.y, hi.x, hi.y);
  }
}

// K1 v12: A in double-buffered LDS (shared by 8 waves), B DIRECT global->reg.
// In the fragment-order image a wave's B-frag set (wc, j, kt) is one
// contiguous 1KB wave-load -> coalesced to VGPRs; B regs double-buffer as
// named bbE/bbO over kt pairs (static indexing, rule #20), prefetched a FULL
// K-tile ahead (wave-private, no barrier coupling). Removes per wave-kt:
// 2 gload16 + 4 ds_read_b128 + B-publish from every barrier; kt boundary is
// counted vmcnt(4) (A's 2 DMAs done, B's 4 loads stay in flight). LDS 49.6
// -> 32.8 KB. 4-sub-phase A schedule kept (round-10's +10%). Round-11
// postmortem: co-residency levers are null; this deletes pipe work instead.
__global__ __launch_bounds__(512, 2) void k_gram(const char* __restrict__ f8p,
                                                 const float* __restrict__ an,
                                                 const float* __restrict__ logits,
                                                 float* __restrict__ S,
                                                 float* __restrict__ rs_part,
                                                 float* __restrict__ S1,
                                                 float* __restrict__ S2,
                                                 float* __restrict__ aff) {
  int x = blockIdx.x & 7, u = blockIdx.x >> 3;
  int t = threadIdx.x, lane = t & 63, wave = t >> 6;
  if (blockIdx.x == 0 && t == 0) aff[0] = 0.f;

  if (u == 80) {  // BN stats: 7 blocks (x<7), class x, seg = wave
    if (x >= 7) return;
    int c = x, seg = wave;
    int r0 = seg * 1792;
    float s1 = 0.f, s2 = 0.f;
    for (int j = lane; j < 1792; j += 64) {
      float v = logits[(size_t)(r0 + j) * 7 + c];
      s1 += v;
      s2 += v * v;
    }
#pragma unroll
    for (int o = 1; o < 64; o <<= 1) {
      s1 += __shfl_xor(s1, o);
      s2 += __shfl_xor(s2, o);
    }
    if (lane == 0) { atomicAdd(&S1[c], s1); atomicAdd(&S2[c], s2); }
    return;
  }

  int cls1, cls2, ti, tj, Sidx;
  bool self;
  if (x < 7 && u < 36) {
    int a = 0, r = u;
    while (r > a) { r -= a + 1; ++a; }  // u = a(a+1)/2 + r, r<=a
    ti = a; tj = r;                     // tj <= ti
    cls1 = x; cls2 = x; Sidx = x; self = true;
  } else {
    int j;
    if (x < 7) j = x * 44 + (u - 36);          // 0..307
    else { if (u >= 76) return; j = 308 + u; } // 308..383
    int p = j >> 6, t64 = j & 63;
    ti = t64 >> 3; tj = t64 & 7;
    cls1 = p + 1; cls2 = 0; Sidx = 7 + p; self = false;
  }

  __shared__ char ldsA[2][16384];
  __shared__ float bacc[8];

  int R0 = cls1 * 2048 + ti * 256;
  int C0 = cls2 * 2048 + tj * 256;

  int wr = wave >> 2, wc = wave & 3;   // 2M x 4N wave grid
  int q = lane >> 4, s = lane & 15;

  // A staging: wave stages chunks {2w, 2w+1} per K-tile
  const char* gA0 = f8p + ((size_t)(R0 >> 4) + wave * 2)     * 8192 + lane * 16;
  const char* gA1 = f8p + ((size_t)(R0 >> 4) + wave * 2 + 1) * 8192 + lane * 16;
  // B direct: frag (j, kt) at gB + j*8192 + kt*1024 (1KB coalesced wave-load)
  const char* gB  = f8p + ((size_t)(C0 >> 4) + wc * 4) * 8192 + lane * 16;

  f32x4 acc[8][4];
#pragma unroll
  for (int i = 0; i < 8; ++i)
#pragma unroll
    for (int j = 0; j < 4; ++j)
      acc[i][j] = (f32x4){0.f, 0.f, 0.f, 0.f};

  longlong2 bbE[4], bbO[4];
  // prologue: B[0] to regs, A[0] to LDS buf 0, full drain + publish
#pragma unroll
  for (int j = 0; j < 4; ++j)
    bbE[j] = *(const longlong2*)(gB + j * 8192);
  gload16(gA0, &ldsA[0][(wave * 2) * 1024 + lane * 16]);
  gload16(gA1, &ldsA[0][(wave * 2 + 1) * 1024 + lane * 16]);
  __syncthreads();

#define MM16(BB_, A0_, A1_, I0_, I1_)                                         \
  do {                                                                        \
    asm volatile("s_waitcnt lgkmcnt(0)" ::: "memory");                        \
    __builtin_amdgcn_sched_barrier(0);                                        \
    __builtin_amdgcn_s_setprio(1);                                            \
    _Pragma("unroll")                                                         \
    for (int j_ = 0; j_ < 4; ++j_)                                            \
      acc[I0_][j_] = __builtin_amdgcn_mfma_f32_16x16x32_fp8_fp8(              \
          A0_.x, BB_[j_].x, acc[I0_][j_], 0, 0, 0);                           \
    _Pragma("unroll")                                                         \
    for (int j_ = 0; j_ < 4; ++j_)                                            \
      acc[I1_][j_] = __builtin_amdgcn_mfma_f32_16x16x32_fp8_fp8(              \
          A1_.x, BB_[j_].x, acc[I1_][j_], 0, 0, 0);                           \
    _Pragma("unroll")                                                         \
    for (int j_ = 0; j_ < 4; ++j_)                                            \
      acc[I0_][j_] = __builtin_amdgcn_mfma_f32_16x16x32_fp8_fp8(              \
          A0_.y, BB_[j_].y, acc[I0_][j_], 0, 0, 0);                           \
    _Pragma("unroll")                                                         \
    for (int j_ = 0; j_ < 4; ++j_)                                            \
      acc[I1_][j_] = __builtin_amdgcn_mfma_f32_16x16x32_fp8_fp8(              \
          A1_.y, BB_[j_].y, acc[I1_][j_], 0, 0, 0);                           \
    __builtin_amdgcn_s_setprio(0);                                            \
  } while (0)

#pragma unroll 1
  for (int h = 0; h < 4; ++h) {
    // ================= kt_e = 2h : A in ldsA[0], B = bbE =================
    {
      const char* LA = &ldsA[0][(wr * 8) * 1024 + lane * 16];
      longlong2 a0, a1;
      // phase 0: i=0,1 ; stage A[kt+1] -> ldsA[1]
      a0 = *(const longlong2*)(LA);
      a1 = *(const longlong2*)(LA + 1024);
      gload16(gA0 + (2 * h + 1) * 1024, &ldsA[1][(wave * 2) * 1024 + lane * 16]);
      gload16(gA1 + (2 * h + 1) * 1024, &ldsA[1][(wave * 2 + 1) * 1024 + lane * 16]);
      MM16(bbE, a0, a1, 0, 1);
      // phase 1: i=2,3 ; load B[kt+1] -> bbO (wave-private, no barrier dep)
      a0 = *(const longlong2*)(LA + 2 * 1024);
      a1 = *(const longlong2*)(LA + 3 * 1024);
      __builtin_amdgcn_s_barrier();
      asm volatile("" ::: "memory");
#pragma unroll
      for (int j = 0; j < 4; ++j)
        bbO[j] = *(const longlong2*)(gB + j * 8192 + (2 * h + 1) * 1024);
      MM16(bbE, a0, a1, 2, 3);
      // phase 2: i=4,5
      a0 = *(const longlong2*)(LA + 4 * 1024);
      a1 = *(const longlong2*)(LA + 5 * 1024);
      __builtin_amdgcn_s_barrier();
      asm volatile("" ::: "memory");
      MM16(bbE, a0, a1, 4, 5);
      // phase 3: i=6,7
      a0 = *(const longlong2*)(LA + 6 * 1024);
      a1 = *(const longlong2*)(LA + 7 * 1024);
      __builtin_amdgcn_s_barrier();
      asm volatile("" ::: "memory");
      MM16(bbE, a0, a1, 6, 7);
      // boundary: A DMAs (oldest) done; B's 4 loads stay in flight
      asm volatile("s_waitcnt vmcnt(4)" ::: "memory");
      __builtin_amdgcn_s_barrier();
      asm volatile("" ::: "memory");
    }
    // ================= kt_o = 2h+1 : A in ldsA[1], B = bbO ===============
    {
      const char* LA = &ldsA[1][(wr * 8) * 1024 + lane * 16];
      longlong2 a0, a1;
      // phase 0: i=0,1 ; stage A[kt+1] -> ldsA[0] (h<3)
      a0 = *(const longlong2*)(LA);
      a1 = *(const longlong2*)(LA + 1024);
      if (h < 3) {
        gload16(gA0 + (2 * h + 2) * 1024, &ldsA[0][(wave * 2) * 1024 + lane * 16]);
        gload16(gA1 + (2 * h + 2) * 1024, &ldsA[0][(wave * 2 + 1) * 1024 + lane * 16]);
      }
      MM16(bbO, a0, a1, 0, 1);
      // phase 1: i=2,3 ; load B[kt+1] -> bbE (h<3)
      a0 = *(const longlong2*)(LA + 2 * 1024);
      a1 = *(const longlong2*)(LA + 3 * 1024);
      __builtin_amdgcn_s_barrier();
      asm volatile("" ::: "memory");
      if (h < 3) {
#pragma unroll
        for (int j = 0; j < 4; ++j)
          bbE[j] = *(const longlong2*)(gB + j * 8192 + (2 * h + 2) * 1024);
      }
      MM16(bbO, a0, a1, 2, 3);
      // phase 2: i=4,5
      a0 = *(const longlong2*)(LA + 4 * 1024);
      a1 = *(const longlong2*)(LA + 5 * 1024);
      __builtin_amdgcn_s_barrier();
      asm volatile("" ::: "memory");
      MM16(bbO, a0, a1, 4, 5);
      // phase 3: i=6,7
      a0 = *(const longlong2*)(LA + 6 * 1024);
      a1 = *(const longlong2*)(LA + 7 * 1024);
      __builtin_amdgcn_s_barrier();
      asm volatile("" ::: "memory");
      MM16(bbO, a0, a1, 6, 7);
      // boundary (skip entirely on last iteration; nothing staged)
      if (h < 3) {
        asm volatile("s_waitcnt vmcnt(4)" ::: "memory");
        __builtin_amdgcn_s_barrier();
        asm volatile("" ::: "memory");
      }
    }
  }
#undef MM16

  // Epilogue. C/D (16x16x32): col=lane&15, row=(lane>>4)*4+reg.
  bool dg = self && (ti == tj);
  bool mirror = self && (ti > tj);
  float blockAcc = 0.f;
  float colAcc[4] = {0.f, 0.f, 0.f, 0.f};
  float anB_[4];
#pragma unroll
  for (int j = 0; j < 4; ++j) anB_[j] = an[C0 + wc * 64 + j * 16 + s];

#pragma unroll
  for (int i = 0; i < 8; ++i) {
    f32x4 anA_ = *(const f32x4*)&an[R0 + wr * 128 + i * 16 + q * 4];
#pragma unroll
    for (int rg = 0; rg < 4; ++rg) {
      int rl = wr * 128 + i * 16 + q * 4 + rg;
      float aA = anA_[rg];
      float rowAcc = 0.f;
#pragma unroll
      for (int j = 0; j < 4; ++j) {
        int cl = wc * 64 + j * 16 + s;
        float g = acc[i][j][rg];
        float d2 = fmaxf(aA + anB_[j] - g * INV_2S2, 0.f);
        if (dg && rl == cl) d2 = 0.f;  // exact diagonal
        float e1 = __expf(-0.05f * d2);
        float e2 = e1 * e1, e4 = e2 * e2, e8 = e4 * e4, e16 = e8 * e8;
        blockAcc += e1 + e2 + e4 + e8 + e16;
        if (self) {
          float ek = __expf(-12.5f * d2);  // KDE: 1/(2*0.2^2)
          rowAcc += ek;
          if (mirror) colAcc[j] += ek;
        }
      }
      if (self) {
        rowAcc += __shfl_xor(rowAcc, 1);
        rowAcc += __shfl_xor(rowAcc, 2);
        rowAcc += __shfl_xor(rowAcc, 4);
        rowAcc += __shfl_xor(rowAcc, 8);
        if (s == 0)
          rs_part[(size_t)(R0 + rl) * 48 + tj * 4 + wc] = rowAcc;
      }
    }
  }
  if (mirror) {
#pragma unroll
    for (int j = 0; j < 4; ++j) {
      float v = colAcc[j];
      v += __shfl_xor(v, 16);
      v += __shfl_xor(v, 32);
      if (q == 0)
        rs_part[(size_t)(C0 + wc * 64 + j * 16 + s) * 48 + 32 + ti * 2 + wr] = v;
    }
    blockAcc *= 2.f;  // mirror tile counted once
  }
#pragma unroll
  for (int o = 1; o < 64; o <<= 1) blockAcc += __shfl_xor(blockAcc, o);
  if (lane == 0) bacc[wave] = blockAcc;
  __syncthreads();
  if (t == 0) {
    float sB = 0.f;
#pragma unroll
    for (int w = 0; w < 8; ++w) sB += bacc[w];
    atomicAdd(&S[Sidx], sB);
  }
}

// K2: bnout (blocks 0..97, 1024 thr) + per-class KDE weight & affinity
// (blocks 98..104). Reads only the valid rs_part slots per block-row bi:
// direct [0, 4bi+4), mirror [34+2bi, 48).
__global__ __launch_bounds__(1024) void k_final(const float* __restrict__ logits,
                                                const float* __restrict__ S1,
                                                const float* __restrict__ S2,
                                                const float* __restrict__ gamma,
                                                const float* __restrict__ beta,
                                                const float* __restrict__ rs_part,
                                                const float* __restrict__ S,
                                                float* __restrict__ out) {
  int b = blockIdx.x, t = threadIdx.x;
  if (b < 98) {
    int idx = b * 1024 + t;  // 98*1024 = 100352 exactly
    int row = idx / 7;
    int c = idx - row * 7;
    float mu = S1[c] * (1.f / 14336.f);
    float var = S2[c] * (1.f / 14336.f) - mu * mu;
    out[idx] = gamma[c] * (logits[idx] - mu) * rsqrtf(var + 1e-5f) + beta[c];
    return;
  }
  int c = b - 98;
  // log_norm = -256*ln(2*pi*0.04) - ln(2048)
  const float LOG_NORM = 345.9110632f;
  float v = 0.f;
  for (int i = t; i < M_CLS; i += 1024) {
    int bi = i >> 8;
    const float* rp = rs_part + (size_t)(c * M_CLS + i) * 48;
    float rsum = 0.f;
    int nd = 4 * bi + 4;
    for (int k = 0; k < nd; ++k) rsum += rp[k];
    for (int k = 34 + 2 * bi; k < 48; ++k) rsum += rp[k];
    v += 1.f / (logf(rsum) + LOG_NORM);
  }
#pragma unroll
  for (int o = 1; o < 64; o <<= 1) v += __shfl_xor(v, o);
  __shared__ float r[16];
  if ((t & 63) == 0) r[t >> 6] = v;
  __syncthreads();
  if (t == 0) {
    float vs = 0.f;
#pragma unroll
    for (int w = 0; w < 16; ++w) vs += r[w];
    float w = 1.f / (vs + 1e-5f);
    const float inv_m2 = 1.0f / ((float)M_CLS * (float)M_CLS);
    float Ssrc = S[c];
    float Stgt = (c > 0) ? S[0] : S[1];
    float X    = (c > 0) ? S[6 + c] : S[7];  // cross Sidx 7+p is (p+1,0)
    float mmd = (Ssrc + Stgt - 2.f * X) * inv_m2;
    atomicAdd(&out[100352], -mmd * w);
  }
}

extern "C" void kernel_launch(void* const* d_in, const int* in_sizes, int n_in,
                              void* d_out, int out_size, void* d_ws, size_t ws_size,
                              hipStream_t stream) {
  const float* fea   = (const float*)d_in[0];
  const float* W_fc  = (const float*)d_in[1];
  const float* gamma = (const float*)d_in[2];
  const float* beta  = (const float*)d_in[3];
  float* out = (float*)d_out;

  char* ws = (char*)d_ws;
  char* f8p = ws;                                // packed fp8 image: 7,340,032 B
  float* fbase   = (float*)(ws + 7340032);
  float* an      = fbase;                        // 14336
  float* logits  = fbase + 14336;                // 100352
  float* zb      = fbase + 114688;               // 64-float zero block
  float* S1      = zb;                           //   [0..6]
  float* S2      = zb + 7;                       //   [7..13]
  float* S       = zb + 16;                      //   [16..28] (13 used)
  float* rs_part = fbase + 114752;               // 14336*48 (valid slots only)

  k_prep <<<896, 256, 0, stream>>>(fea, W_fc, f8p, an, logits, zb);
  k_gram <<<648, 512, 0, stream>>>(f8p, an, logits, S, rs_part, S1, S2,
                                   out + 100352);
  k_final<<<105, 1024, 0, stream>>>(logits, S1, S2, gamma, beta, rs_part, S, out);
}

// Round 13
// 167.996 us; speedup vs baseline: 1.1477x; 1.1477x over previous
//
#include <hip/hip_runtime.h>

#define B_ROWS 14336
#define D_DIM  512
#define C_CLS  7
#define M_CLS  2048

typedef __attribute__((ext_vector_type(4))) float f32x4;

// fp8 scale: fea*64 -> sigma~3.2 in e4m3 range; Gram scaled by 4096
#define FP8_SCALE 64.0f
#define INV_2S2   (2.0f / 4096.0f)

typedef const __attribute__((address_space(1))) char gchar_t;
typedef __attribute__((address_space(3))) char lchar_t;

__device__ __forceinline__ void gload16(const char* g, char* l) {
  // async global->LDS DMA, 16B/lane, dest = wave-uniform base + lane*16
  __builtin_amdgcn_global_load_lds((gchar_t*)g, (lchar_t*)l, 16, 0, 0);
}

// K0: fea->fp8 packed in fragment-order image + row norms + logits + zero zb.
// Image layout: 16B at (r16, kp, l) = byte ((r16*8 + kp)*64 + l)*16, holding
// row r16*16 + (l&15), k-bytes {kp*64 + (l>>4)*8 ..+7} (.x) and {+32..} (.y).
__global__ __launch_bounds__(256) void k_prep(const float* __restrict__ fea,
                                              const float* __restrict__ W,
                                              char* __restrict__ f8p,
                                              float* __restrict__ an,
                                              float* __restrict__ logits,
                                              float* __restrict__ zb) {  // 64 floats
  int t = threadIdx.x, wave = t >> 6, lane = t & 63;
  if (blockIdx.x == 0 && t < 64) zb[t] = 0.f;
  __shared__ char lrow[16 * 528];  // 16 rows x 512B fp8 (+16 pad)

  int r0 = blockIdx.x * 16;
#pragma unroll
  for (int k = 0; k < 4; ++k) {
    int rl = wave * 4 + k;
    int row = r0 + rl;
    const float4* fr4 = (const float4*)(fea + (size_t)row * D_DIM);
    float4 v0 = fr4[lane * 2], v1 = fr4[lane * 2 + 1];

    float p[8];
#pragma unroll
    for (int c = 0; c < 7; ++c) {
      const float4* w4 = (const float4*)(W + c * D_DIM);
      float4 q0 = w4[lane * 2], q1 = w4[lane * 2 + 1];
      p[c] = v0.x * q0.x + v0.y * q0.y + v0.z * q0.z + v0.w * q0.w +
             v1.x * q1.x + v1.y * q1.y + v1.z * q1.z + v1.w * q1.w;
    }
    p[7] = v0.x * v0.x + v0.y * v0.y + v0.z * v0.z + v0.w * v0.w +
           v1.x * v1.x + v1.y * v1.y + v1.z * v1.z + v1.w * v1.w;

#pragma unroll
    for (int c = 0; c < 8; ++c) {
      p[c] += __shfl_xor(p[c], 1);
      p[c] += __shfl_xor(p[c], 2);
      p[c] += __shfl_xor(p[c], 4);
    }
    int v = lane & 7;
    float y = p[0];
    y = (v == 1) ? p[1] : y;
    y = (v == 2) ? p[2] : y;
    y = (v == 3) ? p[3] : y;
    y = (v == 4) ? p[4] : y;
    y = (v == 5) ? p[5] : y;
    y = (v == 6) ? p[6] : y;
    y = (v == 7) ? p[7] : y;
    y += __shfl_xor(y, 8);
    y += __shfl_xor(y, 16);
    y += __shfl_xor(y, 32);
    if (lane < 7) logits[row * 7 + lane] = y;
    else if (lane == 7) an[row] = y;

    int w0 = __builtin_amdgcn_cvt_pk_fp8_f32(v0.x * FP8_SCALE, v0.y * FP8_SCALE, 0, 0);
    w0     = __builtin_amdgcn_cvt_pk_fp8_f32(v0.z * FP8_SCALE, v0.w * FP8_SCALE, w0, 1);
    int w1 = __builtin_amdgcn_cvt_pk_fp8_f32(v1.x * FP8_SCALE, v1.y * FP8_SCALE, 0, 0);
    w1     = __builtin_amdgcn_cvt_pk_fp8_f32(v1.z * FP8_SCALE, v1.w * FP8_SCALE, w1, 1);
    *(int2*)&lrow[rl * 528 + lane * 8] = make_int2(w0, w1);
  }
  __syncthreads();
  int4* outp = (int4*)f8p + (size_t)blockIdx.x * 512;
#pragma unroll
  for (int pi = 0; pi < 2; ++pi) {
    int idx = pi * 256 + t;          // [0,512) = (kp, l)
    int kp = idx >> 6, l = idx & 63;
    int sr = l & 15, qk = l >> 4;
    int2 lo = *(const int2*)&lrow[sr * 528 + kp * 64 + qk * 8];
    int2 hi = *(const int2*)&lrow[sr * 528 + kp * 64 + 32 + qk * 8];
    outp[idx] = make_int4(lo.x, lo.y, hi.x, hi.y);
  }
}

// K1 = v9 (round-10 measured optimum, 74.7us): 256x256 tile, 8 waves 2Mx4N,
// BK=64, DOUBLE-buffered A and B LDS via global_load_lds, XCD-clustered grid
// 648, K-tile fragmented into 4 sub-phases of 16 MFMA with ds_reads issued
// under the prior phase's MFMA shadow and stage DMAs spread over phases 0-1.
// Round-12 postmortem: B-direct-to-reg regressed 76->104us (per-wave VMEM
// issue/delivery stream is the scarcest resource; global_load_lds bypasses
// it) -> reverted verbatim. Occupancy/traffic levers measured null
// (rounds 3,8,11); fine-phase interleave is the one real lever (+10%).
__global__ __launch_bounds__(512, 2) void k_gram(const char* __restrict__ f8p,
                                                 const float* __restrict__ an,
                                                 const float* __restrict__ logits,
                                                 float* __restrict__ S,
                                                 float* __restrict__ rs_part,
                                                 float* __restrict__ S1,
                                                 float* __restrict__ S2,
                                                 float* __restrict__ aff) {
  int x = blockIdx.x & 7, u = blockIdx.x >> 3;
  int t = threadIdx.x, lane = t & 63, wave = t >> 6;
  if (blockIdx.x == 0 && t == 0) aff[0] = 0.f;

  if (u == 80) {  // BN stats: 7 blocks (x<7), class x, seg = wave
    if (x >= 7) return;
    int c = x, seg = wave;
    int r0 = seg * 1792;
    float s1 = 0.f, s2 = 0.f;
    for (int j = lane; j < 1792; j += 64) {
      float v = logits[(size_t)(r0 + j) * 7 + c];
      s1 += v;
      s2 += v * v;
    }
#pragma unroll
    for (int o = 1; o < 64; o <<= 1) {
      s1 += __shfl_xor(s1, o);
      s2 += __shfl_xor(s2, o);
    }
    if (lane == 0) { atomicAdd(&S1[c], s1); atomicAdd(&S2[c], s2); }
    return;
  }

  int cls1, cls2, ti, tj, Sidx;
  bool self;
  if (x < 7 && u < 36) {
    int a = 0, r = u;
    while (r > a) { r -= a + 1; ++a; }  // u = a(a+1)/2 + r, r<=a
    ti = a; tj = r;                     // tj <= ti
    cls1 = x; cls2 = x; Sidx = x; self = true;
  } else {
    int j;
    if (x < 7) j = x * 44 + (u - 36);          // 0..307
    else { if (u >= 76) return; j = 308 + u; } // 308..383
    int p = j >> 6, t64 = j & 63;
    ti = t64 >> 3; tj = t64 & 7;
    cls1 = p + 1; cls2 = 0; Sidx = 7 + p; self = false;
  }

  __shared__ char ldsA[2][16384];
  __shared__ char ldsB[2][16384];
  __shared__ float bacc[8];

  int R0 = cls1 * 2048 + ti * 256;
  int C0 = cls2 * 2048 + tj * 256;

  // staging: wave stages chunks {2w, 2w+1} of A and B per K-tile
  const char* gA0 = f8p + ((size_t)(R0 >> 4) + wave * 2)     * 8192 + lane * 16;
  const char* gA1 = f8p + ((size_t)(R0 >> 4) + wave * 2 + 1) * 8192 + lane * 16;
  const char* gB0 = f8p + ((size_t)(C0 >> 4) + wave * 2)     * 8192 + lane * 16;
  const char* gB1 = f8p + ((size_t)(C0 >> 4) + wave * 2 + 1) * 8192 + lane * 16;

  int wr = wave >> 2, wc = wave & 3;   // 2M x 4N wave grid
  int q = lane >> 4, s = lane & 15;

  f32x4 acc[8][4];
#pragma unroll
  for (int i = 0; i < 8; ++i)
#pragma unroll
    for (int j = 0; j < 4; ++j)
      acc[i][j] = (f32x4){0.f, 0.f, 0.f, 0.f};

  // prologue: stage tile 0 fully, drain, publish
  gload16(gA0, &ldsA[0][(wave * 2) * 1024 + lane * 16]);
  gload16(gA1, &ldsA[0][(wave * 2 + 1) * 1024 + lane * 16]);
  gload16(gB0, &ldsB[0][(wave * 2) * 1024 + lane * 16]);
  gload16(gB1, &ldsB[0][(wave * 2 + 1) * 1024 + lane * 16]);
  __syncthreads();

#define MM16(A0_, A1_, I0_, I1_)                                              \
  do {                                                                        \
    asm volatile("s_waitcnt lgkmcnt(0)" ::: "memory");                        \
    __builtin_amdgcn_sched_barrier(0);                                        \
    __builtin_amdgcn_s_setprio(1);                                            \
    _Pragma("unroll")                                                         \
    for (int j_ = 0; j_ < 4; ++j_)                                            \
      acc[I0_][j_] = __builtin_amdgcn_mfma_f32_16x16x32_fp8_fp8(              \
          A0_.x, bb[j_].x, acc[I0_][j_], 0, 0, 0);                            \
    _Pragma("unroll")                                                         \
    for (int j_ = 0; j_ < 4; ++j_)                                            \
      acc[I1_][j_] = __builtin_amdgcn_mfma_f32_16x16x32_fp8_fp8(              \
          A1_.x, bb[j_].x, acc[I1_][j_], 0, 0, 0);                            \
    _Pragma("unroll")                                                         \
    for (int j_ = 0; j_ < 4; ++j_)                                            \
      acc[I0_][j_] = __builtin_amdgcn_mfma_f32_16x16x32_fp8_fp8(              \
          A0_.y, bb[j_].y, acc[I0_][j_], 0, 0, 0);                            \
    _Pragma("unroll")                                                         \
    for (int j_ = 0; j_ < 4; ++j_)                                            \
      acc[I1_][j_] = __builtin_amdgcn_mfma_f32_16x16x32_fp8_fp8(              \
          A1_.y, bb[j_].y, acc[I1_][j_], 0, 0, 0);                            \
    __builtin_amdgcn_s_setprio(0);                                            \
  } while (0)

#pragma unroll 1
  for (int kt = 0; kt < 8; ++kt) {
    int cur = kt & 1;
    const char* LA = &ldsA[cur][(wr * 8) * 1024 + lane * 16];
    const char* LB = &ldsB[cur][(wc * 4) * 1024 + lane * 16];
    longlong2 a0, a1, bb[4];
    // ---- phase 0: i = 0,1 (loads after boundary barrier; buf published) ----
    a0 = *(const longlong2*)(LA);
    a1 = *(const longlong2*)(LA + 1024);
#pragma unroll
    for (int j = 0; j < 4; ++j) bb[j] = *(const longlong2*)(LB + j * 1024);
    if (kt < 7) {  // stage next tile, part 1 (A chunks)
      int nb = cur ^ 1;
      gload16(gA0 + (kt + 1) * 1024, &ldsA[nb][(wave * 2) * 1024 + lane * 16]);
      gload16(gA1 + (kt + 1) * 1024, &ldsA[nb][(wave * 2 + 1) * 1024 + lane * 16]);
    }
    MM16(a0, a1, 0, 1);
    // ---- phase 1: i = 2,3 (ds issued under phase-0 MFMA shadow) ----
    a0 = *(const longlong2*)(LA + 2 * 1024);
    a1 = *(const longlong2*)(LA + 3 * 1024);
    if (kt < 7) {  // stage next tile, part 2 (B chunks)
      int nb = cur ^ 1;
      gload16(gB0 + (kt + 1) * 1024, &ldsB[nb][(wave * 2) * 1024 + lane * 16]);
      gload16(gB1 + (kt + 1) * 1024, &ldsB[nb][(wave * 2 + 1) * 1024 + lane * 16]);
    }
    __builtin_amdgcn_s_barrier();
    asm volatile("" ::: "memory");
    MM16(a0, a1, 2, 3);
    // ---- phase 2: i = 4,5 ----
    a0 = *(const longlong2*)(LA + 4 * 1024);
    a1 = *(const longlong2*)(LA + 5 * 1024);
    __builtin_amdgcn_s_barrier();
    asm volatile("" ::: "memory");
    MM16(a0, a1, 4, 5);
    // ---- phase 3: i = 6,7 ----
    a0 = *(const longlong2*)(LA + 6 * 1024);
    a1 = *(const longlong2*)(LA + 7 * 1024);
    __builtin_amdgcn_s_barrier();
    asm volatile("" ::: "memory");
    MM16(a0, a1, 6, 7);
    // ---- kt boundary: publish next buffer ----
    if (kt < 7)
      asm volatile("s_waitcnt vmcnt(0)" ::: "memory");  // 4 loads, >=2 phases old
    __builtin_amdgcn_s_barrier();
    asm volatile("" ::: "memory");
  }
#undef MM16

  // Epilogue. C/D (16x16x32): col=lane&15, row=(lane>>4)*4+reg.
  bool dg = self && (ti == tj);
  bool mirror = self && (ti > tj);
  float blockAcc = 0.f;
  float colAcc[4] = {0.f, 0.f, 0.f, 0.f};
  float anB_[4];
#pragma unroll
  for (int j = 0; j < 4; ++j) anB_[j] = an[C0 + wc * 64 + j * 16 + s];

#pragma unroll
  for (int i = 0; i < 8; ++i) {
    f32x4 anA_ = *(const f32x4*)&an[R0 + wr * 128 + i * 16 + q * 4];
#pragma unroll
    for (int rg = 0; rg < 4; ++rg) {
      int rl = wr * 128 + i * 16 + q * 4 + rg;
      float aA = anA_[rg];
      float rowAcc = 0.f;
#pragma unroll
      for (int j = 0; j < 4; ++j) {
        int cl = wc * 64 + j * 16 + s;
        float g = acc[i][j][rg];
        float d2 = fmaxf(aA + anB_[j] - g * INV_2S2, 0.f);
        if (dg && rl == cl) d2 = 0.f;  // exact diagonal
        float e1 = __expf(-0.05f * d2);
        float e2 = e1 * e1, e4 = e2 * e2, e8 = e4 * e4, e16 = e8 * e8;
        blockAcc += e1 + e2 + e4 + e8 + e16;
        if (self) {
          float ek = __expf(-12.5f * d2);  // KDE: 1/(2*0.2^2)
          rowAcc += ek;
          if (mirror) colAcc[j] += ek;
        }
      }
      if (self) {
        rowAcc += __shfl_xor(rowAcc, 1);
        rowAcc += __shfl_xor(rowAcc, 2);
        rowAcc += __shfl_xor(rowAcc, 4);
        rowAcc += __shfl_xor(rowAcc, 8);
        if (s == 0)
          rs_part[(size_t)(R0 + rl) * 48 + tj * 4 + wc] = rowAcc;
      }
    }
  }
  if (mirror) {
#pragma unroll
    for (int j = 0; j < 4; ++j) {
      float v = colAcc[j];
      v += __shfl_xor(v, 16);
      v += __shfl_xor(v, 32);
      if (q == 0)
        rs_part[(size_t)(C0 + wc * 64 + j * 16 + s) * 48 + 32 + ti * 2 + wr] = v;
    }
    blockAcc *= 2.f;  // mirror tile counted once
  }
#pragma unroll
  for (int o = 1; o < 64; o <<= 1) blockAcc += __shfl_xor(blockAcc, o);
  if (lane == 0) bacc[wave] = blockAcc;
  __syncthreads();
  if (t == 0) {
    float sB = 0.f;
#pragma unroll
    for (int w = 0; w < 8; ++w) sB += bacc[w];
    atomicAdd(&S[Sidx], sB);
  }
}

// K2: bnout (blocks 0..97, 1024 thr) + per-class KDE weight & affinity
// (blocks 98..104). KDE gather vectorized (G13): valid slots per block-row
// bi are vector-aligned by construction — direct [0,4bi+4) = (bi+1) float4s;
// mirror [34+2bi,48) = (7-bi) float2s (8B-aligned: 34+2bi even, stride 192B).
__global__ __launch_bounds__(1024) void k_final(const float* __restrict__ logits,
                                                const float* __restrict__ S1,
                                                const float* __restrict__ S2,
                                                const float* __restrict__ gamma,
                                                const float* __restrict__ beta,
                                                const float* __restrict__ rs_part,
                                                const float* __restrict__ S,
                                                float* __restrict__ out) {
  int b = blockIdx.x, t = threadIdx.x;
  if (b < 98) {
    int idx = b * 1024 + t;  // 98*1024 = 100352 exactly
    int row = idx / 7;
    int c = idx - row * 7;
    float mu = S1[c] * (1.f / 14336.f);
    float var = S2[c] * (1.f / 14336.f) - mu * mu;
    out[idx] = gamma[c] * (logits[idx] - mu) * rsqrtf(var + 1e-5f) + beta[c];
    return;
  }
  int c = b - 98;
  // log_norm = -256*ln(2*pi*0.04) - ln(2048)
  const float LOG_NORM = 345.9110632f;
  float v = 0.f;
  for (int i = t; i < M_CLS; i += 1024) {
    int bi = i >> 8;
    const float* rp = rs_part + (size_t)(c * M_CLS + i) * 48;
    float rsum = 0.f;
    const float4* rp4 = (const float4*)rp;
    for (int k = 0; k <= bi; ++k) {           // direct slots, (bi+1) float4s
      float4 xx = rp4[k];
      rsum += xx.x + xx.y + xx.z + xx.w;
    }
    const float2* rp2 = (const float2*)(rp + 34 + 2 * bi);
    for (int k = 0; k < 7 - bi; ++k) {        // mirror slots, (7-bi) float2s
      float2 xx = rp2[k];
      rsum += xx.x + xx.y;
    }
    v += 1.f / (logf(rsum) + LOG_NORM);
  }
#pragma unroll
  for (int o = 1; o < 64; o <<= 1) v += __shfl_xor(v, o);
  __shared__ float r[16];
  if ((t & 63) == 0) r[t >> 6] = v;
  __syncthreads();
  if (t == 0) {
    float vs = 0.f;
#pragma unroll
    for (int w = 0; w < 16; ++w) vs += r[w];
    float w = 1.f / (vs + 1e-5f);
    const float inv_m2 = 1.0f / ((float)M_CLS * (float)M_CLS);
    float Ssrc = S[c];
    float Stgt = (c > 0) ? S[0] : S[1];
    float X    = (c > 0) ? S[6 + c] : S[7];  // cross Sidx 7+p is (p+1,0)
    float mmd = (Ssrc + Stgt - 2.f * X) * inv_m2;
    atomicAdd(&out[100352], -mmd * w);
  }
}

extern "C" void kernel_launch(void* const* d_in, const int* in_sizes, int n_in,
                              void* d_out, int out_size, void* d_ws, size_t ws_size,
                              hipStream_t stream) {
  const float* fea   = (const float*)d_in[0];
  const float* W_fc  = (const float*)d_in[1];
  const float* gamma = (const float*)d_in[2];
  const float* beta  = (const float*)d_in[3];
  float* out = (float*)d_out;

  char* ws = (char*)d_ws;
  char* f8p = ws;                                // packed fp8 image: 7,340,032 B
  float* fbase   = (float*)(ws + 7340032);
  float* an      = fbase;                        // 14336
  float* logits  = fbase + 14336;                // 100352
  float* zb      = fbase + 114688;               // 64-float zero block
  float* S1      = zb;                           //   [0..6]
  float* S2      = zb + 7;                       //   [7..13]
  float* S       = zb + 16;                      //   [16..28] (13 used)
  float* rs_part = fbase + 114752;               // 14336*48 (valid slots only)

  k_prep <<<896, 256, 0, stream>>>(fea, W_fc, f8p, an, logits, zb);
  k_gram <<<648, 512, 0, stream>>>(f8p, an, logits, S, rs_part, S1, S2,
                                   out + 100352);
  k_final<<<105, 1024, 0, stream>>>(logits, S1, S2, gamma, beta, rs_part, S, out);
}

// Round 14
// 156.570 us; speedup vs baseline: 1.2314x; 1.0730x over previous
//
#include <hip/hip_runtime.h>

#define B_ROWS 14336
#define D_DIM  512
#define C_CLS  7
#define M_CLS  2048

typedef __attribute__((ext_vector_type(4))) float f32x4;

// fp8 scale: fea*64 -> sigma~3.2 in e4m3 range; Gram scaled by 4096
#define FP8_SCALE 64.0f
#define INV_2S2   (2.0f / 4096.0f)

typedef const __attribute__((address_space(1))) char gchar_t;
typedef __attribute__((address_space(3))) char lchar_t;

__device__ __forceinline__ void gload16(const char* g, char* l) {
  // async global->LDS DMA, 16B/lane, dest = wave-uniform base + lane*16
  __builtin_amdgcn_global_load_lds((gchar_t*)g, (lchar_t*)l, 16, 0, 0);
}

// K0: fea->fp8 packed in fragment-order image + row norms + logits + zero zb.
// Image layout: 16B at (r16, kp, l) = byte ((r16*8 + kp)*64 + l)*16, holding
// row r16*16 + (l&15), k-bytes {kp*64 + (l>>4)*8 ..+7} (.x) and {+32..} (.y).
__global__ __launch_bounds__(256) void k_prep(const float* __restrict__ fea,
                                              const float* __restrict__ W,
                                              char* __restrict__ f8p,
                                              float* __restrict__ an,
                                              float* __restrict__ logits,
                                              float* __restrict__ zb) {  // 64 floats
  int t = threadIdx.x, wave = t >> 6, lane = t & 63;
  if (blockIdx.x == 0 && t < 64) zb[t] = 0.f;
  __shared__ char lrow[16 * 528];  // 16 rows x 512B fp8 (+16 pad)

  int r0 = blockIdx.x * 16;
#pragma unroll
  for (int k = 0; k < 4; ++k) {
    int rl = wave * 4 + k;
    int row = r0 + rl;
    const float4* fr4 = (const float4*)(fea + (size_t)row * D_DIM);
    float4 v0 = fr4[lane * 2], v1 = fr4[lane * 2 + 1];

    float p[8];
#pragma unroll
    for (int c = 0; c < 7; ++c) {
      const float4* w4 = (const float4*)(W + c * D_DIM);
      float4 q0 = w4[lane * 2], q1 = w4[lane * 2 + 1];
      p[c] = v0.x * q0.x + v0.y * q0.y + v0.z * q0.z + v0.w * q0.w +
             v1.x * q1.x + v1.y * q1.y + v1.z * q1.z + v1.w * q1.w;
    }
    p[7] = v0.x * v0.x + v0.y * v0.y + v0.z * v0.z + v0.w * v0.w +
           v1.x * v1.x + v1.y * v1.y + v1.z * v1.z + v1.w * v1.w;

#pragma unroll
    for (int c = 0; c < 8; ++c) {
      p[c] += __shfl_xor(p[c], 1);
      p[c] += __shfl_xor(p[c], 2);
      p[c] += __shfl_xor(p[c], 4);
    }
    int v = lane & 7;
    float y = p[0];
    y = (v == 1) ? p[1] : y;
    y = (v == 2) ? p[2] : y;
    y = (v == 3) ? p[3] : y;
    y = (v == 4) ? p[4] : y;
    y = (v == 5) ? p[5] : y;
    y = (v == 6) ? p[6] : y;
    y = (v == 7) ? p[7] : y;
    y += __shfl_xor(y, 8);
    y += __shfl_xor(y, 16);
    y += __shfl_xor(y, 32);
    if (lane < 7) logits[row * 7 + lane] = y;
    else if (lane == 7) an[row] = y;

    int w0 = __builtin_amdgcn_cvt_pk_fp8_f32(v0.x * FP8_SCALE, v0.y * FP8_SCALE, 0, 0);
    w0     = __builtin_amdgcn_cvt_pk_fp8_f32(v0.z * FP8_SCALE, v0.w * FP8_SCALE, w0, 1);
    int w1 = __builtin_amdgcn_cvt_pk_fp8_f32(v1.x * FP8_SCALE, v1.y * FP8_SCALE, 0, 0);
    w1     = __builtin_amdgcn_cvt_pk_fp8_f32(v1.z * FP8_SCALE, v1.w * FP8_SCALE, w1, 1);
    *(int2*)&lrow[rl * 528 + lane * 8] = make_int2(w0, w1);
  }
  __syncthreads();
  int4* outp = (int4*)f8p + (size_t)blockIdx.x * 512;
#pragma unroll
  for (int pi = 0; pi < 2; ++pi) {
    int idx = pi * 256 + t;          // [0,512) = (kp, l)
    int kp = idx >> 6, l = idx & 63;
    int sr = l & 15, qk = l >> 4;
    int2 lo = *(const int2*)&lrow[sr * 528 + kp * 64 + qk * 8];
    int2 hi = *(const int2*)&lrow[sr * 528 + kp * 64 + 32 + qk * 8];
    outp[idx] = make_int4(lo.x, lo.y, hi.x, hi.y);
  }
}

// K1 v14: v9's fine-sub-phase schedule at 128x128 tiles, 4 waves (2Mx2N,
// wave = 64x64 = 4x4 frags), BK=64, dbuf A+B LDS via global_load_lds.
// Round-13 analysis: v9 at 8-wave barrier groups has ~10x phase slack
// (310cy MFMA issue vs 2.9k cyc phase wall) — barrier-convoy-bound.
// This halves the barrier group (4 waves), drops LDS to 32.8KB -> 4
// independent barrier groups per CU whose stalls mutually overlap, and
// smooths grid packing (2504 blocks vs 636; 636/512 quantized to 2 rounds).
// 2 sub-phases of 16 MFMA per kt, stage A in phase 0 / B in phase 1,
// vmcnt(0) only at kt boundary. Fragment layout + per-acc K-order identical
// to v9 -> bit-identical Gram.
// Grid 2504 = 313 u x 8 xcd:
//   x<7 : u<136 self class x (tri 16x16); u in [136,311): cross
//         j = x*175 + (u-136)  (j<1225)
//   x==7: u<311 cross j = 1225+u
//   u==311 (all x): BN block idx=x; u==312 (x<6): BN block idx=8+x
// rs_part 64 slots/row: direct tj*2+wc in [0,2bi+2); mirror 32+ti*2+wr in
// [34+2bi,64). Exactly-once; k_final reads only valid ranges.
__global__ __launch_bounds__(256, 4) void k_gram(const char* __restrict__ f8p,
                                                 const float* __restrict__ an,
                                                 const float* __restrict__ logits,
                                                 float* __restrict__ S,
                                                 float* __restrict__ rs_part,
                                                 float* __restrict__ S1,
                                                 float* __restrict__ S2,
                                                 float* __restrict__ aff) {
  int x = blockIdx.x & 7, u = blockIdx.x >> 3;
  int t = threadIdx.x, lane = t & 63, wave = t >> 6;
  if (blockIdx.x == 0 && t == 0) aff[0] = 0.f;

  if (u >= 311) {  // BN stats: 14 blocks x 4 wave-jobs = 56 = (class, seg)
    int blk;
    if (u == 311) blk = x;
    else { if (x >= 6) return; blk = 8 + x; }
    int idx = blk * 4 + wave;          // 0..55
    int c = idx >> 3, seg = idx & 7;
    int r0 = seg * 1792;
    float s1 = 0.f, s2 = 0.f;
    for (int j = lane; j < 1792; j += 64) {
      float v = logits[(size_t)(r0 + j) * 7 + c];
      s1 += v;
      s2 += v * v;
    }
#pragma unroll
    for (int o = 1; o < 64; o <<= 1) {
      s1 += __shfl_xor(s1, o);
      s2 += __shfl_xor(s2, o);
    }
    if (lane == 0) { atomicAdd(&S1[c], s1); atomicAdd(&S2[c], s2); }
    return;
  }

  int cls1, cls2, ti, tj, Sidx;
  bool self;
  if (x < 7 && u < 136) {
    int a = 0, r = u;
    while (r > a) { r -= a + 1; ++a; }  // u = a(a+1)/2 + r, r<=a (a<=15)
    ti = a; tj = r;                     // tj <= ti
    cls1 = x; cls2 = x; Sidx = x; self = true;
  } else {
    int j;
    if (x < 7) j = x * 175 + (u - 136);        // 0..1224
    else j = 1225 + u;                         // 1225..1535
    int p = j >> 8, t256 = j & 255;
    ti = t256 >> 4; tj = t256 & 15;
    cls1 = p + 1; cls2 = 0; Sidx = 7 + p; self = false;
  }

  __shared__ char ldsA[2][8192];
  __shared__ char ldsB[2][8192];
  __shared__ float bacc[4];

  int R0 = cls1 * 2048 + ti * 128;
  int C0 = cls2 * 2048 + tj * 128;

  // staging: wave stages row-group chunks {2w, 2w+1} of A and B per K-tile
  const char* gA0 = f8p + ((size_t)(R0 >> 4) + wave * 2)     * 8192 + lane * 16;
  const char* gA1 = f8p + ((size_t)(R0 >> 4) + wave * 2 + 1) * 8192 + lane * 16;
  const char* gB0 = f8p + ((size_t)(C0 >> 4) + wave * 2)     * 8192 + lane * 16;
  const char* gB1 = f8p + ((size_t)(C0 >> 4) + wave * 2 + 1) * 8192 + lane * 16;

  int wr = wave >> 1, wc = wave & 1;   // 2M x 2N wave grid, wave = 64x64
  int q = lane >> 4, s = lane & 15;

  f32x4 acc[4][4];
#pragma unroll
  for (int i = 0; i < 4; ++i)
#pragma unroll
    for (int j = 0; j < 4; ++j)
      acc[i][j] = (f32x4){0.f, 0.f, 0.f, 0.f};

  // prologue: stage tile 0 fully, drain, publish
  gload16(gA0, &ldsA[0][(wave * 2) * 1024 + lane * 16]);
  gload16(gA1, &ldsA[0][(wave * 2 + 1) * 1024 + lane * 16]);
  gload16(gB0, &ldsB[0][(wave * 2) * 1024 + lane * 16]);
  gload16(gB1, &ldsB[0][(wave * 2 + 1) * 1024 + lane * 16]);
  __syncthreads();

#define MM16(A0_, A1_, I0_, I1_)                                              \
  do {                                                                        \
    asm volatile("s_waitcnt lgkmcnt(0)" ::: "memory");                        \
    __builtin_amdgcn_sched_barrier(0);                                        \
    __builtin_amdgcn_s_setprio(1);                                            \
    _Pragma("unroll")                                                         \
    for (int j_ = 0; j_ < 4; ++j_)                                            \
      acc[I0_][j_] = __builtin_amdgcn_mfma_f32_16x16x32_fp8_fp8(              \
          A0_.x, bb[j_].x, acc[I0_][j_], 0, 0, 0);                            \
    _Pragma("unroll")                                                         \
    for (int j_ = 0; j_ < 4; ++j_)                                            \
      acc[I1_][j_] = __builtin_amdgcn_mfma_f32_16x16x32_fp8_fp8(              \
          A1_.x, bb[j_].x, acc[I1_][j_], 0, 0, 0);                            \
    _Pragma("unroll")                                                         \
    for (int j_ = 0; j_ < 4; ++j_)                                            \
      acc[I0_][j_] = __builtin_amdgcn_mfma_f32_16x16x32_fp8_fp8(              \
          A0_.y, bb[j_].y, acc[I0_][j_], 0, 0, 0);                            \
    _Pragma("unroll")                                                         \
    for (int j_ = 0; j_ < 4; ++j_)                                            \
      acc[I1_][j_] = __builtin_amdgcn_mfma_f32_16x16x32_fp8_fp8(              \
          A1_.y, bb[j_].y, acc[I1_][j_], 0, 0, 0);                            \
    __builtin_amdgcn_s_setprio(0);                                            \
  } while (0)

#pragma unroll 1
  for (int kt = 0; kt < 8; ++kt) {
    int cur = kt & 1;
    const char* LA = &ldsA[cur][(wr * 4) * 1024 + lane * 16];
    const char* LB = &ldsB[cur][(wc * 4) * 1024 + lane * 16];
    longlong2 a0, a1, bb[4];
    // ---- phase 0: i = 0,1 ----
    a0 = *(const longlong2*)(LA);
    a1 = *(const longlong2*)(LA + 1024);
#pragma unroll
    for (int j = 0; j < 4; ++j) bb[j] = *(const longlong2*)(LB + j * 1024);
    if (kt < 7) {  // stage next tile, part 1 (A chunks)
      int nb = cur ^ 1;
      gload16(gA0 + (kt + 1) * 1024, &ldsA[nb][(wave * 2) * 1024 + lane * 16]);
      gload16(gA1 + (kt + 1) * 1024, &ldsA[nb][(wave * 2 + 1) * 1024 + lane * 16]);
    }
    MM16(a0, a1, 0, 1);
    // ---- phase 1: i = 2,3 (ds issued under phase-0 MFMA shadow) ----
    a0 = *(const longlong2*)(LA + 2 * 1024);
    a1 = *(const longlong2*)(LA + 3 * 1024);
    if (kt < 7) {  // stage next tile, part 2 (B chunks)
      int nb = cur ^ 1;
      gload16(gB0 + (kt + 1) * 1024, &ldsB[nb][(wave * 2) * 1024 + lane * 16]);
      gload16(gB1 + (kt + 1) * 1024, &ldsB[nb][(wave * 2 + 1) * 1024 + lane * 16]);
    }
    __builtin_amdgcn_s_barrier();
    asm volatile("" ::: "memory");
    MM16(a0, a1, 2, 3);
    // ---- kt boundary: publish next buffer (4 loads, >=1 phase old) ----
    if (kt < 7)
      asm volatile("s_waitcnt vmcnt(0)" ::: "memory");
    __builtin_amdgcn_s_barrier();
    asm volatile("" ::: "memory");
  }
#undef MM16

  // Epilogue. C/D (16x16x32): col=lane&15, row=(lane>>4)*4+reg.
  bool dg = self && (ti == tj);
  bool mirror = self && (ti > tj);
  float blockAcc = 0.f;
  float colAcc[4] = {0.f, 0.f, 0.f, 0.f};
  float anB_[4];
#pragma unroll
  for (int j = 0; j < 4; ++j) anB_[j] = an[C0 + wc * 64 + j * 16 + s];

#pragma unroll
  for (int i = 0; i < 4; ++i) {
    f32x4 anA_ = *(const f32x4*)&an[R0 + wr * 64 + i * 16 + q * 4];
#pragma unroll
    for (int rg = 0; rg < 4; ++rg) {
      int rl = wr * 64 + i * 16 + q * 4 + rg;
      float aA = anA_[rg];
      float rowAcc = 0.f;
#pragma unroll
      for (int j = 0; j < 4; ++j) {
        int cl = wc * 64 + j * 16 + s;
        float g = acc[i][j][rg];
        float d2 = fmaxf(aA + anB_[j] - g * INV_2S2, 0.f);
        if (dg && rl == cl) d2 = 0.f;  // exact diagonal
        float e1 = __expf(-0.05f * d2);
        float e2 = e1 * e1, e4 = e2 * e2, e8 = e4 * e4, e16 = e8 * e8;
        blockAcc += e1 + e2 + e4 + e8 + e16;
        if (self) {
          float ek = __expf(-12.5f * d2);  // KDE: 1/(2*0.2^2)
          rowAcc += ek;
          if (mirror) colAcc[j] += ek;
        }
      }
      if (self) {
        rowAcc += __shfl_xor(rowAcc, 1);
        rowAcc += __shfl_xor(rowAcc, 2);
        rowAcc += __shfl_xor(rowAcc, 4);
        rowAcc += __shfl_xor(rowAcc, 8);
        if (s == 0)
          rs_part[(size_t)(R0 + rl) * 64 + tj * 2 + wc] = rowAcc;
      }
    }
  }
  if (mirror) {
#pragma unroll
    for (int j = 0; j < 4; ++j) {
      float v = colAcc[j];
      v += __shfl_xor(v, 16);
      v += __shfl_xor(v, 32);
      if (q == 0)
        rs_part[(size_t)(C0 + wc * 64 + j * 16 + s) * 64 + 32 + ti * 2 + wr] = v;
    }
    blockAcc *= 2.f;  // mirror tile counted once
  }
#pragma unroll
  for (int o = 1; o < 64; o <<= 1) blockAcc += __shfl_xor(blockAcc, o);
  if (lane == 0) bacc[wave] = blockAcc;
  __syncthreads();
  if (t == 0)
    atomicAdd(&S[Sidx], bacc[0] + bacc[1] + bacc[2] + bacc[3]);
}

// K2: bnout (blocks 0..97, 1024 thr) + per-class KDE weight & affinity
// (blocks 98..104). rs_part 64 slots/row; valid per block-row bi (128-row
// blocks): direct [0,2bi+2) = (bi+1) float2s; mirror [34+2bi,64) = (15-bi)
// float2s (8B-aligned: even offsets, 256B row stride).
__global__ __launch_bounds__(1024) void k_final(const float* __restrict__ logits,
                                                const float* __restrict__ S1,
                                                const float* __restrict__ S2,
                                                const float* __restrict__ gamma,
                                                const float* __restrict__ beta,
                                                const float* __restrict__ rs_part,
                                                const float* __restrict__ S,
                                                float* __restrict__ out) {
  int b = blockIdx.x, t = threadIdx.x;
  if (b < 98) {
    int idx = b * 1024 + t;  // 98*1024 = 100352 exactly
    int row = idx / 7;
    int c = idx - row * 7;
    float mu = S1[c] * (1.f / 14336.f);
    float var = S2[c] * (1.f / 14336.f) - mu * mu;
    out[idx] = gamma[c] * (logits[idx] - mu) * rsqrtf(var + 1e-5f) + beta[c];
    return;
  }
  int c = b - 98;
  // log_norm = -256*ln(2*pi*0.04) - ln(2048)
  const float LOG_NORM = 345.9110632f;
  float v = 0.f;
  for (int i = t; i < M_CLS; i += 1024) {
    int bi = i >> 7;                          // 128-row block index (0..15)
    const float* rp = rs_part + (size_t)(c * M_CLS + i) * 64;
    float rsum = 0.f;
    const float2* rpd = (const float2*)rp;
    for (int k = 0; k <= bi; ++k) {           // direct: (bi+1) float2s
      float2 xx = rpd[k];
      rsum += xx.x + xx.y;
    }
    const float2* rpm = (const float2*)(rp + 34 + 2 * bi);
    for (int k = 0; k < 15 - bi; ++k) {       // mirror: (15-bi) float2s
      float2 xx = rpm[k];
      rsum += xx.x + xx.y;
    }
    v += 1.f / (logf(rsum) + LOG_NORM);
  }
#pragma unroll
  for (int o = 1; o < 64; o <<= 1) v += __shfl_xor(v, o);
  __shared__ float r[16];
  if ((t & 63) == 0) r[t >> 6] = v;
  __syncthreads();
  if (t == 0) {
    float vs = 0.f;
#pragma unroll
    for (int w = 0; w < 16; ++w) vs += r[w];
    float w = 1.f / (vs + 1e-5f);
    const float inv_m2 = 1.0f / ((float)M_CLS * (float)M_CLS);
    float Ssrc = S[c];
    float Stgt = (c > 0) ? S[0] : S[1];
    float X    = (c > 0) ? S[6 + c] : S[7];  // cross Sidx 7+p is (p+1,0)
    float mmd = (Ssrc + Stgt - 2.f * X) * inv_m2;
    atomicAdd(&out[100352], -mmd * w);
  }
}

extern "C" void kernel_launch(void* const* d_in, const int* in_sizes, int n_in,
                              void* d_out, int out_size, void* d_ws, size_t ws_size,
                              hipStream_t stream) {
  const float* fea   = (const float*)d_in[0];
  const float* W_fc  = (const float*)d_in[1];
  const float* gamma = (const float*)d_in[2];
  const float* beta  = (const float*)d_in[3];
  float* out = (float*)d_out;

  char* ws = (char*)d_ws;
  char* f8p = ws;                                // packed fp8 image: 7,340,032 B
  float* fbase   = (float*)(ws + 7340032);
  float* an      = fbase;                        // 14336
  float* logits  = fbase + 14336;                // 100352
  float* zb      = fbase + 114688;               // 64-float zero block
  float* S1      = zb;                           //   [0..6]
  float* S2      = zb + 7;                       //   [7..13]
  float* S       = zb + 16;                      //   [16..28] (13 used)
  float* rs_part = fbase + 114752;               // 14336*64 (valid slots only)

  k_prep <<<896,  256, 0, stream>>>(fea, W_fc, f8p, an, logits, zb);
  k_gram <<<2504, 256, 0, stream>>>(f8p, an, logits, S, rs_part, S1, S2,
                                    out + 100352);
  k_final<<<105, 1024, 0, stream>>>(logits, S1, S2, gamma, beta, rs_part, S, out);
}